// Round 4
// baseline (612.654 us; speedup 1.0000x reference)
//
#include <hip/hip_runtime.h>

// Problem constants
#define B_   8
#define NT_  512
#define NC_  2048
#define EMB_ 512
#define H_   8
// DK = DV = 64

typedef __attribute__((ext_vector_type(8))) short bf16x8;
typedef __attribute__((ext_vector_type(4))) float f32x4;

__device__ __forceinline__ unsigned short f2bf(float x) {
    unsigned u = __float_as_uint(x);
    u += 0x7fffu + ((u >> 16) & 1u);          // RNE
    return (unsigned short)(u >> 16);
}
// 2x fp32 -> packed bf16x2 in one VALU op (RNE), gfx950-native.
__device__ __forceinline__ unsigned pkbf(float lo, float hi) {
    unsigned r;
    asm("v_cvt_pk_bf16_f32 %0, %1, %2" : "=v"(r) : "v"(lo), "v"(hi));
    return r;
}

// XOR-swizzled LDS tile index: rows of 64 bf16, 8-elem (16B) granules.
__device__ __forceinline__ int swz(int row, int col) {
    return row * 64 + ((((col >> 3) ^ row) & 7) << 3) + (col & 7);
}

// MFMA operand fragment from a swizzled 64-col LDS tile:
// elem j of lane L holds T[rowbase + (L&15)][kq + (L>>4)*8 + j]
__device__ __forceinline__ bf16x8 ldfrag(const unsigned short* t, int rowbase, int kq) {
    int lane = threadIdx.x & 63;
    int m = rowbase + (lane & 15);
    int k = kq + ((lane >> 4) << 3);
    return *(const bf16x8*)(t + swz(m, k));
}

// MFMA operand fragment DIRECT from global bf16 (row-major, leading dim ld):
// elem j of lane L holds base[(rowbase + (L&15))*ld + kq + ((L>>4)&3)*8 + j]
__device__ __forceinline__ bf16x8 gfrag(const unsigned short* base, int rowbase, int ld, int kq) {
    int lane = threadIdx.x & 63;
    return *(const bf16x8*)(base + (size_t)(rowbase + (lane & 15)) * ld + kq + (((lane >> 4) & 3) << 3));
}

// Same, DIRECT from fp32 global with in-register bf16 pack (2 dwordx4 + 4 cvt_pk).
__device__ __forceinline__ bf16x8 gfrag_f32(const float* base, int rowbase, int ld, int kq) {
    int lane = threadIdx.x & 63;
    const float* p = base + (size_t)(rowbase + (lane & 15)) * ld + kq + (((lane >> 4) & 3) << 3);
    float4 a = ((const float4*)p)[0];
    float4 b = ((const float4*)p)[1];
    union { uint4 u4; bf16x8 h; } cvt;
    cvt.u4.x = pkbf(a.x, a.y);
    cvt.u4.y = pkbf(a.z, a.w);
    cvt.u4.z = pkbf(b.x, b.y);
    cvt.u4.w = pkbf(b.z, b.w);
    return cvt.h;
}

// ---------------------------------------------------------------------------
// One-shot weight conversion: 4 matrices of 512x512 fp32 -> bf16 (row-major kept).
// ---------------------------------------------------------------------------
__global__ __launch_bounds__(256) void cvtw(const float* w0, const float* w1,
                                            const float* w2, const float* w3,
                                            unsigned short* dst)
{
    int idx = blockIdx.x * 256 + threadIdx.x;     // 131072 threads x 8 floats
    int m = idx >> 15;
    int off = (idx & 32767) * 8;
    const float* src = m == 0 ? w0 : m == 1 ? w1 : m == 2 ? w2 : w3;
    float4 a = ((const float4*)(src + off))[0];
    float4 b = ((const float4*)(src + off))[1];
    uint4 u;
    u.x = pkbf(a.x, a.y);
    u.y = pkbf(a.z, a.w);
    u.z = pkbf(b.x, b.y);
    u.w = pkbf(b.z, b.w);
    *(uint4*)(dst + (size_t)m * 262144 + off) = u;
}

// ---------------------------------------------------------------------------
// C = A(Mx512) @ W(512x512)^T + bias, 64x64 block tile, 4 waves.
// LDS-FREE: all MFMA fragments loaded directly from global (L1/L2-hot panels).
// A is fp32 (ABF=false, packed in regs) or bf16 (ABF=true). W is bf16.
// mode 0: bf16 out, head-major, ROW-NORMALIZED (q/k projections)
// mode 1: bf16 out, d-major transposed (v projection)
// mode 2: fp32 out, row-major (final out projection)
// ---------------------------------------------------------------------------
template<bool ABF>
__device__ __forceinline__ void gemm_core(const void* A, const unsigned short* W,
                                          const float* bias, void* dst, int sh, int mode,
                                          int r0, int n0)
{
    int tid = threadIdx.x;
    int w = tid >> 6, quad = (tid >> 4) & 3, l16 = tid & 15;
    f32x4 acc[4] = {};

#pragma unroll 2
    for (int k0 = 0; k0 < 512; k0 += 64) {
#pragma unroll
        for (int ks = 0; ks < 2; ks++) {
            bf16x8 af = ABF ? gfrag((const unsigned short*)A, r0 + 16 * w, 512, k0 + 32 * ks)
                            : gfrag_f32((const float*)A, r0 + 16 * w, 512, k0 + 32 * ks);
#pragma unroll
            for (int nt = 0; nt < 4; nt++) {
                bf16x8 bfr = gfrag(W, n0 + 16 * nt, 512, k0 + 32 * ks);
                acc[nt] = __builtin_amdgcn_mfma_f32_16x16x32_bf16(af, bfr, acc[nt], 0, 0, 0);
            }
        }
    }

    float vals[4][4];
    float bn[4];
#pragma unroll
    for (int nt = 0; nt < 4; nt++) bn[nt] = bias[n0 + nt * 16 + l16];
#pragma unroll
    for (int nt = 0; nt < 4; nt++)
#pragma unroll
        for (int r = 0; r < 4; r++) vals[nt][r] = acc[nt][r] + bn[nt];

    if (mode == 0) {
        // fused row-normalize: row's 64 d-values live across l16 group x 4 nt regs
#pragma unroll
        for (int r = 0; r < 4; r++) {
            float ss = 0.f;
#pragma unroll
            for (int nt = 0; nt < 4; nt++) ss += vals[nt][r] * vals[nt][r];
#pragma unroll
            for (int m = 1; m <= 8; m <<= 1) ss += __shfl_xor(ss, m, 64);
            float sc = rsqrtf(fmaxf(ss, 1e-24f));
#pragma unroll
            for (int nt = 0; nt < 4; nt++) vals[nt][r] *= sc;
        }
    }

#pragma unroll
    for (int nt = 0; nt < 4; nt++) {
        int n = n0 + nt * 16 + l16;
        int h = n >> 6, d = n & 63;
#pragma unroll
        for (int r = 0; r < 4; r++) {
            int row = r0 + w * 16 + quad * 4 + r;
            float val = vals[nt][r];
            if (mode == 0) {
                int b = row >> sh, nloc = row & ((1 << sh) - 1);
                ((unsigned short*)dst)[((((size_t)(b * H_ + h) << sh) + nloc) << 6) + d] = f2bf(val);
            } else if (mode == 1) {
                int b = row >> sh, nloc = row & ((1 << sh) - 1);
                ((unsigned short*)dst)[(((size_t)((b * H_ + h) * 64 + d)) << sh) + nloc] = f2bf(val);
            } else {
                ((float*)dst)[(size_t)row * 512 + n] = val;
            }
        }
    }
}

// All three projections in ONE launch: z=0 queries (M=4096), z=1 keys, z=2 values.
__global__ __launch_bounds__(256, 4) void proj3(const float* q, const float* k,
                                                const float* v, const unsigned short* wb,
                                                const float* bAt, const float* bAc, const float* bBc,
                                                unsigned short* qh, unsigned short* kh, unsigned short* vt)
{
    int z = blockIdx.z;
    int r0 = blockIdx.x * 64, n0 = blockIdx.y * 64;
    if (z == 0) {
        if (r0 >= 4096) return;
        gemm_core<false>(q, wb, bAt, qh, 9, 0, r0, n0);
    } else if (z == 1) {
        gemm_core<false>(k, wb + 262144, bAc, kh, 11, 0, r0, n0);
    } else {
        gemm_core<false>(v, wb + 524288, bBc, vt, 11, 1, r0, n0);
    }
}

__global__ __launch_bounds__(256, 4) void outproj(const unsigned short* oh, const unsigned short* wR,
                                                  const float* bR, float* out0)
{
    gemm_core<true>(oh, wR, bR, out0, 0, 2, blockIdx.x * 64, blockIdx.y * 64);
}

// ---------------------------------------------------------------------------
// Fused attention, direct-fragment version. LDS = only Pt (8.6 KB).
// Per (bh, 32-row t-tile):
//   Phase 1 (per 128-c chunk, 2 barriers): S = q̂k̂^T with K-frags direct from
//     global (L2-hot); p = exp(S) (|S|<=1, no max needed); row-sums in regs;
//     p -> bf16 Pt; PV with V-frags direct from global.
//   Reduce -> invs[32]; scale oacc, store oh.
//   Phase 3 (ZERO barriers): recompute S^T = mfma(K,Q) so each lane holds 4
//     consecutive c -> dwordx4 nontemporal att stores (268 MB stream).
// ---------------------------------------------------------------------------
__global__ __launch_bounds__(256, 4) void attn_fused(const unsigned short* qh,
                                                     const unsigned short* kh,
                                                     const unsigned short* vt,
                                                     float* attout,
                                                     unsigned short* oh)
{
    __shared__ unsigned short Pt[2][32 * 64];   // 8 KB: exp(S) tile, 2 c-halves
    __shared__ float red[4][32];
    __shared__ float invs[32];
    int bh = blockIdx.y;
    int t0 = blockIdx.x * 32;
    int tid = threadIdx.x;
    int w = tid >> 6, quad = (tid >> 4) & 3, l16 = tid & 15;

    const unsigned short* qbase = qh + ((size_t)bh * NT_ + t0) * 64;
    const unsigned short* kbase = kh + (size_t)bh * NC_ * 64;
    const unsigned short* vbase = vt + (size_t)bh * 64 * NC_;

    // q fragments direct from global, invariant over the c-loop
    bf16x8 qf[2][2];
#pragma unroll
    for (int mt = 0; mt < 2; mt++)
#pragma unroll
        for (int ks = 0; ks < 2; ks++) qf[mt][ks] = gfrag(qbase, 16 * mt, 64, 32 * ks);

    f32x4 oacc[2] = {};        // O rows 16*mt + quad*4 + r, d-col 16*w + l16
    float rs[2][4] = {};       // per-lane partial row sums [mt][r]

    // ---- phase 1: online QK^T -> exp -> rowsum + PV ----
    for (int c0 = 0; c0 < NC_; c0 += 128) {
#pragma unroll
        for (int nt = 0; nt < 2; nt++) {
            int cl = 32 * w + 16 * nt;          // block-local c window
            int half = cl >> 6, cc = cl & 63;
            bf16x8 kf0 = gfrag(kbase, c0 + cl, 64, 0);
            bf16x8 kf1 = gfrag(kbase, c0 + cl, 64, 32);
#pragma unroll
            for (int mt = 0; mt < 2; mt++) {
                f32x4 acc = {};
                acc = __builtin_amdgcn_mfma_f32_16x16x32_bf16(qf[mt][0], kf0, acc, 0, 0, 0);
                acc = __builtin_amdgcn_mfma_f32_16x16x32_bf16(qf[mt][1], kf1, acc, 0, 0, 0);
#pragma unroll
                for (int r = 0; r < 4; r++) {
                    int t = 16 * mt + quad * 4 + r;
                    float p = __expf(acc[r]);
                    rs[mt][r] += p;
                    Pt[half][swz(t, cc + l16)] = f2bf(p);
                }
            }
        }
        __syncthreads();        // Pt writes visible
#pragma unroll
        for (int half = 0; half < 2; half++) {
#pragma unroll
            for (int ks = 0; ks < 2; ks++) {
                bf16x8 vfr = gfrag(vbase, 16 * w, NC_, c0 + 64 * half + 32 * ks);
#pragma unroll
                for (int mt = 0; mt < 2; mt++) {
                    bf16x8 af = ldfrag((unsigned short*)Pt[half], 16 * mt, 32 * ks);
                    oacc[mt] = __builtin_amdgcn_mfma_f32_16x16x32_bf16(af, vfr, oacc[mt], 0, 0, 0);
                }
            }
        }
        __syncthreads();        // Pt reads done before next chunk overwrites
    }

    // ---- rowsum reduce: l16 shfl (each wave covered disjoint c) + cross-wave LDS ----
#pragma unroll
    for (int mt = 0; mt < 2; mt++)
#pragma unroll
        for (int r = 0; r < 4; r++) {
            float s = rs[mt][r];
#pragma unroll
            for (int m = 1; m <= 8; m <<= 1) s += __shfl_xor(s, m, 64);
            if (l16 == 0) red[w][16 * mt + quad * 4 + r] = s;
        }
    __syncthreads();
    if (tid < 32) invs[tid] = 1.0f / (red[0][tid] + red[1][tid] + red[2][tid] + red[3][tid]);
    __syncthreads();

    // ---- O epilogue: scale by invs, store bf16 head-major ----
    {
        int b = bh >> 3, h = bh & 7;
        int d = 16 * w + l16;
#pragma unroll
        for (int mt = 0; mt < 2; mt++)
#pragma unroll
            for (int r = 0; r < 4; r++) {
                int t = 16 * mt + quad * 4 + r;
                oh[(size_t)(b * NT_ + t0 + t) * 512 + h * 64 + d] = f2bf(oacc[mt][r] * invs[t]);
            }
    }

    // ---- phase 3: recompute S^T = mfma(K,Q), stream att as dwordx4 (no barriers) ----
    float* attbase = attout + ((size_t)bh * NT_ + t0) * 2048;
    float myinv[2];
    myinv[0] = invs[l16];
    myinv[1] = invs[16 + l16];

    for (int c0 = 32 * w; c0 < NC_; c0 += 128) {       // waves own disjoint c stripes
#pragma unroll
        for (int nt = 0; nt < 2; nt++) {
            int cb = c0 + 16 * nt;
            bf16x8 af0 = gfrag(kbase, cb, 64, 0);      // A = K rows (c)
            bf16x8 af1 = gfrag(kbase, cb, 64, 32);
#pragma unroll
            for (int mt = 0; mt < 2; mt++) {
                f32x4 acc = {};
                acc = __builtin_amdgcn_mfma_f32_16x16x32_bf16(af0, qf[mt][0], acc, 0, 0, 0);
                acc = __builtin_amdgcn_mfma_f32_16x16x32_bf16(af1, qf[mt][1], acc, 0, 0, 0);
                // D[c' = quad*4+r][t' = l16]: lane holds 4 CONSECUTIVE c for one t
                f32x4 o;
#pragma unroll
                for (int r = 0; r < 4; r++) o[r] = __expf(acc[r]) * myinv[mt];
                __builtin_nontemporal_store(o,
                    (f32x4*)(attbase + (size_t)(16 * mt + l16) * 2048 + cb + quad * 4));
            }
        }
    }
}

// ---------------------------------------------------------------------------
extern "C" void kernel_launch(void* const* d_in, const int* in_sizes, int n_in,
                              void* d_out, int out_size, void* d_ws, size_t ws_size,
                              hipStream_t stream)
{
    (void)in_sizes; (void)n_in; (void)out_size; (void)ws_size;
    const float* queries = (const float*)d_in[0];
    const float* keys    = (const float*)d_in[1];
    const float* values  = (const float*)d_in[2];
    const float* W_At    = (const float*)d_in[3];
    const float* b_At    = (const float*)d_in[4];
    const float* W_Ac    = (const float*)d_in[5];
    const float* b_Ac    = (const float*)d_in[6];
    const float* W_Bc    = (const float*)d_in[7];
    const float* b_Bc    = (const float*)d_in[8];
    const float* W_R     = (const float*)d_in[9];
    const float* b_R     = (const float*)d_in[10];

    float* out0   = (float*)d_out;
    float* attout = out0 + (size_t)B_ * NT_ * EMB_;

    // Workspace: 22,020,096 shorts = 44 MB (same footprint as the last PASSING round)
    unsigned short* ws = (unsigned short*)d_ws;
    unsigned short* wb = ws;                          // 4 x (512x512) bf16 weights
    unsigned short* qh = ws + 1048576;                // (B,H,NT,64) bf16, normalized
    unsigned short* kh = ws + 3145728;                // (B,H,NC,64) bf16, normalized
    unsigned short* vt = ws + 11534336;               // (B,H,64,NC) bf16 d-major
    unsigned short* oh = ws + 19922944;               // (B,NT,H*64) bf16

    dim3 blk(256);

    // one-shot weight fp32->bf16 (W_At, W_Ac, W_Bc, W_R)
    cvtw<<<dim3(512), blk, 0, stream>>>(W_At, W_Ac, W_Bc, W_R, wb);

    // all three projections, one launch (q/k with fused row-normalization)
    proj3<<<dim3(256, 8, 3), blk, 0, stream>>>(queries, keys, values, wb,
                                               b_At, b_Ac, b_Bc, qh, kh, vt);

    // fused scores + online softmax + PV, then att recompute-and-stream
    attn_fused<<<dim3(NT_ / 32, B_ * H_), blk, 0, stream>>>(qh, kh, vt, attout, oh);

    // out = O @ W_R^T + b_R
    outproj<<<dim3(64, 8), blk, 0, stream>>>(oh, wb + 786432, b_R, out0);
}

// Round 5
// 501.157 us; speedup vs baseline: 1.2225x; 1.2225x over previous
//
#include <hip/hip_runtime.h>

// Problem constants
#define B_   8
#define NT_  512
#define NC_  2048
#define EMB_ 512
#define H_   8
// DK = DV = 64

typedef __attribute__((ext_vector_type(8))) short bf16x8;
typedef __attribute__((ext_vector_type(4))) float f32x4;

__device__ __forceinline__ unsigned short f2bf(float x) {
    unsigned u = __float_as_uint(x);
    u += 0x7fffu + ((u >> 16) & 1u);          // RNE
    return (unsigned short)(u >> 16);
}
// 2x fp32 -> packed bf16x2 in one VALU op (RNE), gfx950-native.
__device__ __forceinline__ unsigned pkbf(float lo, float hi) {
    unsigned r;
    asm("v_cvt_pk_bf16_f32 %0, %1, %2" : "=v"(r) : "v"(lo), "v"(hi));
    return r;
}

// XOR-swizzled LDS tile index: rows of 64 bf16, 8-elem (16B) granules.
__device__ __forceinline__ int swz(int row, int col) {
    return row * 64 + ((((col >> 3) ^ row) & 7) << 3) + (col & 7);
}

// MFMA operand fragment from a swizzled 64-col LDS tile:
// elem j of lane L holds T[rowbase + (L&15)][kq + (L>>4)*8 + j]
__device__ __forceinline__ bf16x8 ldfrag(const unsigned short* t, int rowbase, int kq) {
    int lane = threadIdx.x & 63;
    int m = rowbase + (lane & 15);
    int k = kq + ((lane >> 4) << 3);
    return *(const bf16x8*)(t + swz(m, k));
}

// MFMA operand fragment DIRECT from global bf16 (row-major, leading dim ld).
__device__ __forceinline__ bf16x8 gfrag(const unsigned short* base, int rowbase, int ld, int kq) {
    int lane = threadIdx.x & 63;
    return *(const bf16x8*)(base + (size_t)(rowbase + (lane & 15)) * ld + kq + (((lane >> 4) & 3) << 3));
}

// Stage a 64-col x (NCH*32)-row bf16 tile into swizzled LDS (coalesced uint4 loads).
template<int NCH>
__device__ __forceinline__ void stage_bf(unsigned short* tile, const unsigned short* src, int ld) {
    int tid = threadIdx.x;
#pragma unroll
    for (int i = 0; i < NCH; i++) {
        int ch  = tid + i * 256;
        int row = ch >> 3, c8 = ch & 7;
        uint4 u = *(const uint4*)(src + (size_t)row * ld + c8 * 8);
        *(uint4*)(tile + row * 64 + (((c8 ^ row) & 7) << 3)) = u;
    }
}

// ---------------------------------------------------------------------------
// One-shot weight conversion: 4 matrices of 512x512 fp32 -> bf16 (row-major kept).
// ---------------------------------------------------------------------------
__global__ __launch_bounds__(256) void cvtw(const float* w0, const float* w1,
                                            const float* w2, const float* w3,
                                            unsigned short* dst)
{
    int idx = blockIdx.x * 256 + threadIdx.x;     // 131072 threads x 8 floats
    int m = idx >> 15;
    int off = (idx & 32767) * 8;
    const float* src = m == 0 ? w0 : m == 1 ? w1 : m == 2 ? w2 : w3;
    float4 a = ((const float4*)(src + off))[0];
    float4 b = ((const float4*)(src + off))[1];
    uint4 u;
    u.x = pkbf(a.x, a.y);
    u.y = pkbf(a.z, a.w);
    u.z = pkbf(b.x, b.y);
    u.w = pkbf(b.z, b.w);
    *(uint4*)(dst + (size_t)m * 262144 + off) = u;
}

// ---------------------------------------------------------------------------
// C = A(Mx512) @ W(512x512)^T + bias, 64x64 block tile, 4 waves.
// Double-buffered LDS pipeline (T14 async-stage split):
//   prologue stages k-tile 0; each iter issues coalesced loads for tile k+1
//   into regs, computes tile k from LDS, writes regs->LDS(other buf), ONE barrier.
// A fp32 (ABF=false, reg-converted via cvt_pk) or bf16 (ABF=true). W bf16.
// mode 0: bf16 out, head-major, ROW-NORMALIZED (q/k projections)
// mode 1: bf16 out, d-major transposed (v projection)
// mode 2: fp32 out, row-major (final out projection)
// ---------------------------------------------------------------------------
template<bool ABF>
__device__ __forceinline__ void gemm_core(const void* A, const unsigned short* W,
                                          const float* bias, void* dst, int sh, int mode,
                                          int r0, int n0)
{
    __shared__ unsigned short As[2][64 * 64];   // 16 KB
    __shared__ unsigned short Bs[2][64 * 64];   // 16 KB
    int tid = threadIdx.x;
    int w = tid >> 6, quad = (tid >> 4) & 3, l16 = tid & 15;
    f32x4 acc[4] = {};

    // per-thread staging coords (2 chunks of 32 rows each)
    float4 ra[2][2];    // A fp32 path
    uint4  rab[2];      // A bf16 path
    uint4  rb[2];       // W bf16

    auto LOAD = [&](int k0) {
#pragma unroll
        for (int i = 0; i < 2; i++) {
            int ch = tid + i * 256, row = ch >> 3, c8 = ch & 7;
            if (ABF) {
                rab[i] = *(const uint4*)((const unsigned short*)A + (size_t)(r0 + row) * 512 + k0 + c8 * 8);
            } else {
                const float4* p = (const float4*)((const float*)A + (size_t)(r0 + row) * 512 + k0 + c8 * 8);
                ra[i][0] = p[0]; ra[i][1] = p[1];
            }
            rb[i] = *(const uint4*)(W + (size_t)(n0 + row) * 512 + k0 + c8 * 8);
        }
    };
    auto WRITE = [&](int buf) {
#pragma unroll
        for (int i = 0; i < 2; i++) {
            int ch = tid + i * 256, row = ch >> 3, c8 = ch & 7;
            int off = row * 64 + (((c8 ^ row) & 7) << 3);
            uint4 ua;
            if (ABF) ua = rab[i];
            else {
                ua.x = pkbf(ra[i][0].x, ra[i][0].y);
                ua.y = pkbf(ra[i][0].z, ra[i][0].w);
                ua.z = pkbf(ra[i][1].x, ra[i][1].y);
                ua.w = pkbf(ra[i][1].z, ra[i][1].w);
            }
            *(uint4*)(&As[buf][off]) = ua;
            *(uint4*)(&Bs[buf][off]) = rb[i];
        }
    };

    LOAD(0);
    WRITE(0);
    __syncthreads();
#pragma unroll
    for (int kt = 0; kt < 8; kt++) {
        int cur = kt & 1;
        if (kt < 7) LOAD((kt + 1) * 64);        // in flight during compute
#pragma unroll
        for (int ks = 0; ks < 2; ks++) {
            bf16x8 af = ldfrag(As[cur], 16 * w, 32 * ks);
#pragma unroll
            for (int nt = 0; nt < 4; nt++) {
                bf16x8 bfr = ldfrag(Bs[cur], 16 * nt, 32 * ks);
                acc[nt] = __builtin_amdgcn_mfma_f32_16x16x32_bf16(af, bfr, acc[nt], 0, 0, 0);
            }
        }
        if (kt < 7) {
            WRITE(cur ^ 1);                     // waits vmcnt; latency was covered
            __syncthreads();
        }
    }

    float vals[4][4];
    float bn[4];
#pragma unroll
    for (int nt = 0; nt < 4; nt++) bn[nt] = bias[n0 + nt * 16 + l16];
#pragma unroll
    for (int nt = 0; nt < 4; nt++)
#pragma unroll
        for (int r = 0; r < 4; r++) vals[nt][r] = acc[nt][r] + bn[nt];

    if (mode == 0) {
        // fused row-normalize: row's 64 d-values live across l16 group x 4 nt regs
#pragma unroll
        for (int r = 0; r < 4; r++) {
            float ss = 0.f;
#pragma unroll
            for (int nt = 0; nt < 4; nt++) ss += vals[nt][r] * vals[nt][r];
#pragma unroll
            for (int m = 1; m <= 8; m <<= 1) ss += __shfl_xor(ss, m, 64);
            float sc = rsqrtf(fmaxf(ss, 1e-24f));
#pragma unroll
            for (int nt = 0; nt < 4; nt++) vals[nt][r] *= sc;
        }
    }

#pragma unroll
    for (int nt = 0; nt < 4; nt++) {
        int n = n0 + nt * 16 + l16;
        int h = n >> 6, d = n & 63;
#pragma unroll
        for (int r = 0; r < 4; r++) {
            int row = r0 + w * 16 + quad * 4 + r;
            float val = vals[nt][r];
            if (mode == 0) {
                int b = row >> sh, nloc = row & ((1 << sh) - 1);
                ((unsigned short*)dst)[((((size_t)(b * H_ + h) << sh) + nloc) << 6) + d] = f2bf(val);
            } else if (mode == 1) {
                int b = row >> sh, nloc = row & ((1 << sh) - 1);
                ((unsigned short*)dst)[(((size_t)((b * H_ + h) * 64 + d)) << sh) + nloc] = f2bf(val);
            } else {
                ((float*)dst)[(size_t)row * 512 + n] = val;
            }
        }
    }
}

// All three projections in ONE launch, flattened grid x = {q:64 | k:256 | v:256} blocks.
__global__ __launch_bounds__(256, 4) void proj3(const float* q, const float* k,
                                                const float* v, const unsigned short* wb,
                                                const float* bAt, const float* bAc, const float* bBc,
                                                unsigned short* qh, unsigned short* kh, unsigned short* vt)
{
    int bx = blockIdx.x;
    int n0 = blockIdx.y * 64;
    if (bx < 64) {
        gemm_core<false>(q, wb, bAt, qh, 9, 0, bx * 64, n0);
    } else if (bx < 320) {
        gemm_core<false>(k, wb + 262144, bAc, kh, 11, 0, (bx - 64) * 64, n0);
    } else {
        gemm_core<false>(v, wb + 524288, bBc, vt, 11, 1, (bx - 320) * 64, n0);
    }
}

__global__ __launch_bounds__(256, 4) void outproj(const unsigned short* oh, const unsigned short* wR,
                                                  const float* bR, float* out0)
{
    gemm_core<true>(oh, wR, bR, out0, 0, 2, blockIdx.x * 64, blockIdx.y * 64);
}

// ---------------------------------------------------------------------------
// Fused attention (round-2 measured-good phase 1 + proven S^T phase 3).
// Per (bh, 32-row t-tile):
//   Phase 1 (per 128-c chunk): LDS-stage K(128x64)+V(2x64x64); S = q̂k̂^T;
//     p = exp(S) (|S|<=1); row-sums in regs; p -> bf16 Pt; PV from Pt & Vs.
//   Reduce -> invs[32]; scale oacc, store oh.
//   Phase 3: re-stage K, recompute S^T = mfma(K,Q) so each lane holds 4
//     consecutive c -> dwordx4 nontemporal att stores (268 MB stream).
// ---------------------------------------------------------------------------
__global__ __launch_bounds__(256, 3) void attn_fused(const unsigned short* qh,
                                                     const unsigned short* kh,
                                                     const unsigned short* vt,
                                                     float* attout,
                                                     unsigned short* oh)
{
    __shared__ unsigned short Ks[128 * 64];    // 16 KB   K tile (c-major rows)
    __shared__ unsigned short Vs[2][64 * 64];  // 16 KB   V tile (d-major rows), 2 c-halves
    __shared__ unsigned short Pt[2][32 * 64];  // 8 KB    exp(S) tile, 2 c-halves
    __shared__ float red[4][32];
    __shared__ float invs[32];
    int bh = blockIdx.y;
    int t0 = blockIdx.x * 32;
    int tid = threadIdx.x;
    int w = tid >> 6, quad = (tid >> 4) & 3, l16 = tid & 15;

    const unsigned short* qbase = qh + ((size_t)bh * NT_ + t0) * 64;
    const unsigned short* kbase = kh + (size_t)bh * NC_ * 64;
    const unsigned short* vbase = vt + (size_t)bh * 64 * NC_;

    // q fragments direct from global (one-time, 2KB region), invariant over c-loop
    bf16x8 qf[2][2];
#pragma unroll
    for (int mt = 0; mt < 2; mt++)
#pragma unroll
        for (int ks = 0; ks < 2; ks++) qf[mt][ks] = gfrag(qbase, 16 * mt, 64, 32 * ks);

    f32x4 oacc[2] = {};        // O rows 16*mt + quad*4 + r, d-col 16*w + l16
    float rs[2][4] = {};       // per-lane partial row sums [mt][r]

    // ---- phase 1: online QK^T -> exp -> rowsum + PV ----
    for (int c0 = 0; c0 < NC_; c0 += 128) {
        __syncthreads();
        stage_bf<4>(Ks, kbase + (size_t)c0 * 64, 64);
        stage_bf<2>(Vs[0], vbase + c0, NC_);
        stage_bf<2>(Vs[1], vbase + c0 + 64, NC_);
        __syncthreads();
#pragma unroll
        for (int nt = 0; nt < 2; nt++) {
            int cl = 32 * w + 16 * nt;          // block-local c window
            int half = cl >> 6, cc = cl & 63;
#pragma unroll
            for (int mt = 0; mt < 2; mt++) {
                f32x4 acc = {};
#pragma unroll
                for (int ks = 0; ks < 2; ks++) {
                    bf16x8 bfr = ldfrag(Ks, cl, 32 * ks);
                    acc = __builtin_amdgcn_mfma_f32_16x16x32_bf16(qf[mt][ks], bfr, acc, 0, 0, 0);
                }
#pragma unroll
                for (int r = 0; r < 4; r++) {
                    int t = 16 * mt + quad * 4 + r;
                    float p = __expf(acc[r]);
                    rs[mt][r] += p;
                    Pt[half][swz(t, cc + l16)] = f2bf(p);
                }
            }
        }
        __syncthreads();        // Pt writes visible
#pragma unroll
        for (int half = 0; half < 2; half++) {
#pragma unroll
            for (int ks = 0; ks < 2; ks++) {
                bf16x8 vfr = ldfrag(Vs[half], 16 * w, 32 * ks);   // wave w owns d 16w..16w+15
#pragma unroll
                for (int mt = 0; mt < 2; mt++) {
                    bf16x8 af = ldfrag((unsigned short*)Pt[half], 16 * mt, 32 * ks);
                    oacc[mt] = __builtin_amdgcn_mfma_f32_16x16x32_bf16(af, vfr, oacc[mt], 0, 0, 0);
                }
            }
        }
    }
    __syncthreads();

    // ---- rowsum reduce: l16 shfl (each wave covered disjoint c) + cross-wave LDS ----
#pragma unroll
    for (int mt = 0; mt < 2; mt++)
#pragma unroll
        for (int r = 0; r < 4; r++) {
            float s = rs[mt][r];
#pragma unroll
            for (int m = 1; m <= 8; m <<= 1) s += __shfl_xor(s, m, 64);
            if (l16 == 0) red[w][16 * mt + quad * 4 + r] = s;
        }
    __syncthreads();
    if (tid < 32) invs[tid] = 1.0f / (red[0][tid] + red[1][tid] + red[2][tid] + red[3][tid]);
    __syncthreads();

    // ---- O epilogue: scale by invs, store bf16 head-major ----
    {
        int b = bh >> 3, h = bh & 7;
        int d = 16 * w + l16;
#pragma unroll
        for (int mt = 0; mt < 2; mt++)
#pragma unroll
            for (int r = 0; r < 4; r++) {
                int t = 16 * mt + quad * 4 + r;
                oh[(size_t)(b * NT_ + t0 + t) * 512 + h * 64 + d] = f2bf(oacc[mt][r] * invs[t]);
            }
    }

    // ---- phase 3: recompute S^T = mfma(K,Q) from staged K, dwordx4 att stream ----
    float* attbase = attout + ((size_t)bh * NT_ + t0) * 2048;
    float myinv[2];
    myinv[0] = invs[l16];
    myinv[1] = invs[16 + l16];

    for (int c0 = 0; c0 < NC_; c0 += 128) {
        __syncthreads();
        stage_bf<4>(Ks, kbase + (size_t)c0 * 64, 64);
        __syncthreads();
#pragma unroll
        for (int nt = 0; nt < 2; nt++) {
            int cl = 32 * w + 16 * nt;
            bf16x8 af0 = ldfrag(Ks, cl, 0);    // A = K rows (c)
            bf16x8 af1 = ldfrag(Ks, cl, 32);
#pragma unroll
            for (int mt = 0; mt < 2; mt++) {
                f32x4 acc = {};
                acc = __builtin_amdgcn_mfma_f32_16x16x32_bf16(af0, qf[mt][0], acc, 0, 0, 0);
                acc = __builtin_amdgcn_mfma_f32_16x16x32_bf16(af1, qf[mt][1], acc, 0, 0, 0);
                // D[c' = quad*4+r][t' = l16]: lane holds 4 CONSECUTIVE c for one t
                f32x4 o;
#pragma unroll
                for (int r = 0; r < 4; r++) o[r] = __expf(acc[r]) * myinv[mt];
                __builtin_nontemporal_store(o,
                    (f32x4*)(attbase + (size_t)(16 * mt + l16) * 2048 + c0 + cl + quad * 4));
            }
        }
    }
}

// ---------------------------------------------------------------------------
extern "C" void kernel_launch(void* const* d_in, const int* in_sizes, int n_in,
                              void* d_out, int out_size, void* d_ws, size_t ws_size,
                              hipStream_t stream)
{
    (void)in_sizes; (void)n_in; (void)out_size; (void)ws_size;
    const float* queries = (const float*)d_in[0];
    const float* keys    = (const float*)d_in[1];
    const float* values  = (const float*)d_in[2];
    const float* W_At    = (const float*)d_in[3];
    const float* b_At    = (const float*)d_in[4];
    const float* W_Ac    = (const float*)d_in[5];
    const float* b_Ac    = (const float*)d_in[6];
    const float* W_Bc    = (const float*)d_in[7];
    const float* b_Bc    = (const float*)d_in[8];
    const float* W_R     = (const float*)d_in[9];
    const float* b_R     = (const float*)d_in[10];

    float* out0   = (float*)d_out;
    float* attout = out0 + (size_t)B_ * NT_ * EMB_;

    // Workspace: 22,020,096 shorts = 44 MB (known-safe footprint)
    unsigned short* ws = (unsigned short*)d_ws;
    unsigned short* wb = ws;                          // 4 x (512x512) bf16 weights
    unsigned short* qh = ws + 1048576;                // (B,H,NT,64) bf16, normalized
    unsigned short* kh = ws + 3145728;                // (B,H,NC,64) bf16, normalized
    unsigned short* vt = ws + 11534336;               // (B,H,64,NC) bf16 d-major
    unsigned short* oh = ws + 19922944;               // (B,NT,H*64) bf16

    dim3 blk(256);

    // one-shot weight fp32->bf16 (W_At, W_Ac, W_Bc, W_R)
    cvtw<<<dim3(512), blk, 0, stream>>>(W_At, W_Ac, W_Bc, W_R, wb);

    // all three projections, one launch (q/k with fused row-normalization)
    proj3<<<dim3(576, 8), blk, 0, stream>>>(queries, keys, values, wb,
                                            b_At, b_Ac, b_Bc, qh, kh, vt);

    // fused scores + online softmax + PV, then att recompute-and-stream
    attn_fused<<<dim3(NT_ / 32, B_ * H_), blk, 0, stream>>>(qh, kh, vt, attout, oh);

    // out = O @ W_R^T + b_R
    outproj<<<dim3(64, 8), blk, 0, stream>>>(oh, wb + 786432, b_R, out0);
}

// Round 6
// 484.311 us; speedup vs baseline: 1.2650x; 1.0348x over previous
//
#include <hip/hip_runtime.h>

// Problem constants
#define B_   8
#define NT_  512
#define NC_  2048
#define EMB_ 512
#define H_   8
// DK = DV = 64

typedef __attribute__((ext_vector_type(8))) short bf16x8;
typedef __attribute__((ext_vector_type(4))) float f32x4;

__device__ __forceinline__ unsigned short f2bf(float x) {
    unsigned u = __float_as_uint(x);
    u += 0x7fffu + ((u >> 16) & 1u);          // RNE
    return (unsigned short)(u >> 16);
}
// 2x fp32 -> packed bf16x2 in one VALU op (RNE), gfx950-native.
__device__ __forceinline__ unsigned pkbf(float lo, float hi) {
    unsigned r;
    asm("v_cvt_pk_bf16_f32 %0, %1, %2" : "=v"(r) : "v"(lo), "v"(hi));
    return r;
}

// XOR-swizzled LDS tile index: rows of 64 bf16, 8-elem (16B) granules.
__device__ __forceinline__ int swz(int row, int col) {
    return row * 64 + ((((col >> 3) ^ row) & 7) << 3) + (col & 7);
}

// MFMA operand fragment from a swizzled 64-col LDS tile:
// elem j of lane L holds T[rowbase + (L&15)][kq + (L>>4)*8 + j]
__device__ __forceinline__ bf16x8 ldfrag(const unsigned short* t, int rowbase, int kq) {
    int lane = threadIdx.x & 63;
    int m = rowbase + (lane & 15);
    int k = kq + ((lane >> 4) << 3);
    return *(const bf16x8*)(t + swz(m, k));
}

// MFMA operand fragment DIRECT from global bf16 (row-major, leading dim ld).
__device__ __forceinline__ bf16x8 gfrag(const unsigned short* base, int rowbase, int ld, int kq) {
    int lane = threadIdx.x & 63;
    return *(const bf16x8*)(base + (size_t)(rowbase + (lane & 15)) * ld + kq + (((lane >> 4) & 3) << 3));
}

// Stage a 64-col x (NCH*32)-row bf16 tile into swizzled LDS (coalesced uint4 loads).
template<int NCH>
__device__ __forceinline__ void stage_bf(unsigned short* tile, const unsigned short* src, int ld) {
    int tid = threadIdx.x;
#pragma unroll
    for (int i = 0; i < NCH; i++) {
        int ch  = tid + i * 256;
        int row = ch >> 3, c8 = ch & 7;
        uint4 u = *(const uint4*)(src + (size_t)row * ld + c8 * 8);
        *(uint4*)(tile + row * 64 + (((c8 ^ row) & 7) << 3)) = u;
    }
}

// ---------------------------------------------------------------------------
// One-shot weight conversion: 4 matrices of 512x512 fp32 -> bf16 (row-major kept).
// ---------------------------------------------------------------------------
__global__ __launch_bounds__(256) void cvtw(const float* w0, const float* w1,
                                            const float* w2, const float* w3,
                                            unsigned short* dst)
{
    int idx = blockIdx.x * 256 + threadIdx.x;     // 131072 threads x 8 floats
    int m = idx >> 15;
    int off = (idx & 32767) * 8;
    const float* src = m == 0 ? w0 : m == 1 ? w1 : m == 2 ? w2 : w3;
    float4 a = ((const float4*)(src + off))[0];
    float4 b = ((const float4*)(src + off))[1];
    uint4 u;
    u.x = pkbf(a.x, a.y);
    u.y = pkbf(a.z, a.w);
    u.z = pkbf(b.x, b.y);
    u.w = pkbf(b.z, b.w);
    *(uint4*)(dst + (size_t)m * 262144 + off) = u;
}

// ---------------------------------------------------------------------------
// 128x128-tile projection GEMM: C = A(Mx512 fp32) @ W(512x512 bf16)^T + bias.
// 4 waves as 2x2, each wave owns a 64x64 sub-tile (4x4 16x16 fragments).
// Per BK=64 k-tile per wave: 32 MFMA vs 16 ds_read_b128 (2:1) -- vs 64-tile's
// 8:10. Double-buffered LDS (2x 128x64 A + B = 64 KB), reg-prefetch staging.
// mode 0: bf16 out, head-major, ROW-NORMALIZED (q/k; 64-col wave == one head)
// mode 1: bf16 out, d-major transposed (v)
// ---------------------------------------------------------------------------
__device__ __forceinline__ void gemm_core128(const float* A, const unsigned short* W,
                                             const float* bias, unsigned short* dst,
                                             int sh, int mode, int r0, int n0)
{
    __shared__ unsigned short As[2][128 * 64];  // 32 KB
    __shared__ unsigned short Bs[2][128 * 64];  // 32 KB
    int tid = threadIdx.x;
    int w = tid >> 6, quad = (tid >> 4) & 3, l16 = tid & 15;
    int wr = w >> 1, wc = w & 1;                // 2x2 wave grid
    f32x4 acc[4][4] = {};                       // [mt][nt]

    // staging regs: 4 chunks of 32 rows each (rows = ch>>3, col-granule = ch&7)
    float4 ra[4][2];
    uint4  rb[4];

    auto LOAD = [&](int k0) {
#pragma unroll
        for (int i = 0; i < 4; i++) {
            int ch = tid + i * 256, row = ch >> 3, c8 = ch & 7;
            const float4* p = (const float4*)(A + (size_t)(r0 + row) * 512 + k0 + c8 * 8);
            ra[i][0] = p[0]; ra[i][1] = p[1];
            rb[i] = *(const uint4*)(W + (size_t)(n0 + row) * 512 + k0 + c8 * 8);
        }
    };
    auto WRITE = [&](int buf) {
#pragma unroll
        for (int i = 0; i < 4; i++) {
            int ch = tid + i * 256, row = ch >> 3, c8 = ch & 7;
            int off = row * 64 + (((c8 ^ row) & 7) << 3);
            uint4 ua;
            ua.x = pkbf(ra[i][0].x, ra[i][0].y);
            ua.y = pkbf(ra[i][0].z, ra[i][0].w);
            ua.z = pkbf(ra[i][1].x, ra[i][1].y);
            ua.w = pkbf(ra[i][1].z, ra[i][1].w);
            *(uint4*)(&As[buf][off]) = ua;
            *(uint4*)(&Bs[buf][off]) = rb[i];
        }
    };

    LOAD(0);
    WRITE(0);
    __syncthreads();
    for (int kt = 0; kt < 8; kt++) {
        int cur = kt & 1;
        if (kt < 7) LOAD((kt + 1) * 64);        // in flight during compute
#pragma unroll
        for (int ks = 0; ks < 2; ks++) {
#pragma unroll
            for (int mt = 0; mt < 4; mt++) {
                bf16x8 af = ldfrag(As[cur], 64 * wr + 16 * mt, 32 * ks);
#pragma unroll
                for (int nt = 0; nt < 4; nt++) {
                    bf16x8 bfr = ldfrag(Bs[cur], 64 * wc + 16 * nt, 32 * ks);
                    acc[mt][nt] = __builtin_amdgcn_mfma_f32_16x16x32_bf16(af, bfr, acc[mt][nt], 0, 0, 0);
                }
            }
        }
        if (kt < 7) {
            WRITE(cur ^ 1);                     // waits vmcnt; latency was covered
            __syncthreads();
        }
    }

    float bn[4];
#pragma unroll
    for (int nt = 0; nt < 4; nt++) bn[nt] = bias[n0 + 64 * wc + nt * 16 + l16];

    // epilogue per mt (limits live range): wave's 64 cols = exactly one head
#pragma unroll
    for (int mt = 0; mt < 4; mt++) {
        float vals[4][4];
#pragma unroll
        for (int nt = 0; nt < 4; nt++)
#pragma unroll
            for (int r = 0; r < 4; r++) vals[nt][r] = acc[mt][nt][r] + bn[nt];

        if (mode == 0) {
#pragma unroll
            for (int r = 0; r < 4; r++) {
                float ss = 0.f;
#pragma unroll
                for (int nt = 0; nt < 4; nt++) ss += vals[nt][r] * vals[nt][r];
#pragma unroll
                for (int m = 1; m <= 8; m <<= 1) ss += __shfl_xor(ss, m, 64);
                float sc = rsqrtf(fmaxf(ss, 1e-24f));
#pragma unroll
                for (int nt = 0; nt < 4; nt++) vals[nt][r] *= sc;
            }
        }

#pragma unroll
        for (int nt = 0; nt < 4; nt++) {
            int n = n0 + 64 * wc + nt * 16 + l16;
            int h = n >> 6, d = n & 63;
#pragma unroll
            for (int r = 0; r < 4; r++) {
                int row = r0 + 64 * wr + 16 * mt + quad * 4 + r;
                int b = row >> sh, nloc = row & ((1 << sh) - 1);
                if (mode == 0)
                    dst[((((size_t)(b * H_ + h) << sh) + nloc) << 6) + d] = f2bf(vals[nt][r]);
                else
                    dst[(((size_t)((b * H_ + h) * 64 + d)) << sh) + nloc] = f2bf(vals[nt][r]);
            }
        }
    }
}

// All three projections in ONE launch, flattened grid x = {q:32 | k:128 | v:128} M-tiles.
__global__ __launch_bounds__(256, 2) void proj3(const float* q, const float* k,
                                                const float* v, const unsigned short* wb,
                                                const float* bAt, const float* bAc, const float* bBc,
                                                unsigned short* qh, unsigned short* kh, unsigned short* vt)
{
    int bx = blockIdx.x;
    int n0 = blockIdx.y * 128;
    if (bx < 32) {
        gemm_core128(q, wb, bAt, qh, 9, 0, bx * 128, n0);
    } else if (bx < 160) {
        gemm_core128(k, wb + 262144, bAc, kh, 11, 0, (bx - 32) * 128, n0);
    } else {
        gemm_core128(v, wb + 524288, bBc, vt, 11, 1, (bx - 160) * 128, n0);
    }
}

// ---------------------------------------------------------------------------
// 64x64 dbuf GEMM core (bf16 A) -- kept for the final out-projection.
// mode 2: fp32 out, row-major.
// ---------------------------------------------------------------------------
__global__ __launch_bounds__(256, 4) void outproj(const unsigned short* oh, const unsigned short* W,
                                                  const float* bR, float* out0)
{
    __shared__ unsigned short As[2][64 * 64];
    __shared__ unsigned short Bs[2][64 * 64];
    int r0 = blockIdx.x * 64, n0 = blockIdx.y * 64;
    int tid = threadIdx.x;
    int w = tid >> 6, quad = (tid >> 4) & 3, l16 = tid & 15;
    f32x4 acc[4] = {};

    uint4 rab[2], rb[2];
    auto LOAD = [&](int k0) {
#pragma unroll
        for (int i = 0; i < 2; i++) {
            int ch = tid + i * 256, row = ch >> 3, c8 = ch & 7;
            rab[i] = *(const uint4*)(oh + (size_t)(r0 + row) * 512 + k0 + c8 * 8);
            rb[i]  = *(const uint4*)(W + (size_t)(n0 + row) * 512 + k0 + c8 * 8);
        }
    };
    auto WRITE = [&](int buf) {
#pragma unroll
        for (int i = 0; i < 2; i++) {
            int ch = tid + i * 256, row = ch >> 3, c8 = ch & 7;
            int off = row * 64 + (((c8 ^ row) & 7) << 3);
            *(uint4*)(&As[buf][off]) = rab[i];
            *(uint4*)(&Bs[buf][off]) = rb[i];
        }
    };

    LOAD(0);
    WRITE(0);
    __syncthreads();
#pragma unroll
    for (int kt = 0; kt < 8; kt++) {
        int cur = kt & 1;
        if (kt < 7) LOAD((kt + 1) * 64);
#pragma unroll
        for (int ks = 0; ks < 2; ks++) {
            bf16x8 af = ldfrag(As[cur], 16 * w, 32 * ks);
#pragma unroll
            for (int nt = 0; nt < 4; nt++) {
                bf16x8 bfr = ldfrag(Bs[cur], 16 * nt, 32 * ks);
                acc[nt] = __builtin_amdgcn_mfma_f32_16x16x32_bf16(af, bfr, acc[nt], 0, 0, 0);
            }
        }
        if (kt < 7) {
            WRITE(cur ^ 1);
            __syncthreads();
        }
    }

#pragma unroll
    for (int nt = 0; nt < 4; nt++) {
        int n = n0 + nt * 16 + l16;
        float bn = bR[n];
#pragma unroll
        for (int r = 0; r < 4; r++) {
            int row = r0 + w * 16 + quad * 4 + r;
            out0[(size_t)row * 512 + n] = acc[nt][r] + bn;
        }
    }
}

// ---------------------------------------------------------------------------
// Fused attention (round-2 measured-good phase 1 + proven S^T phase 3).
// Per (bh, 32-row t-tile):
//   Phase 1 (per 128-c chunk): LDS-stage K(128x64)+V(2x64x64); S = q̂k̂^T;
//     p = exp(S) (|S|<=1); row-sums in regs; p -> bf16 Pt; PV from Pt & Vs.
//   Reduce -> invs[32]; scale oacc, store oh.
//   Phase 3: re-stage K, recompute S^T = mfma(K,Q) so each lane holds 4
//     consecutive c -> dwordx4 nontemporal att stores (268 MB stream).
// ---------------------------------------------------------------------------
__global__ __launch_bounds__(256, 3) void attn_fused(const unsigned short* qh,
                                                     const unsigned short* kh,
                                                     const unsigned short* vt,
                                                     float* attout,
                                                     unsigned short* oh)
{
    __shared__ unsigned short Ks[128 * 64];    // 16 KB   K tile (c-major rows)
    __shared__ unsigned short Vs[2][64 * 64];  // 16 KB   V tile (d-major rows), 2 c-halves
    __shared__ unsigned short Pt[2][32 * 64];  // 8 KB    exp(S) tile, 2 c-halves
    __shared__ float red[4][32];
    __shared__ float invs[32];
    int bh = blockIdx.y;
    int t0 = blockIdx.x * 32;
    int tid = threadIdx.x;
    int w = tid >> 6, quad = (tid >> 4) & 3, l16 = tid & 15;

    const unsigned short* qbase = qh + ((size_t)bh * NT_ + t0) * 64;
    const unsigned short* kbase = kh + (size_t)bh * NC_ * 64;
    const unsigned short* vbase = vt + (size_t)bh * 64 * NC_;

    // q fragments direct from global (one-time, 2KB region), invariant over c-loop
    bf16x8 qf[2][2];
#pragma unroll
    for (int mt = 0; mt < 2; mt++)
#pragma unroll
        for (int ks = 0; ks < 2; ks++) qf[mt][ks] = gfrag(qbase, 16 * mt, 64, 32 * ks);

    f32x4 oacc[2] = {};        // O rows 16*mt + quad*4 + r, d-col 16*w + l16
    float rs[2][4] = {};       // per-lane partial row sums [mt][r]

    // ---- phase 1: online QK^T -> exp -> rowsum + PV ----
    for (int c0 = 0; c0 < NC_; c0 += 128) {
        __syncthreads();
        stage_bf<4>(Ks, kbase + (size_t)c0 * 64, 64);
        stage_bf<2>(Vs[0], vbase + c0, NC_);
        stage_bf<2>(Vs[1], vbase + c0 + 64, NC_);
        __syncthreads();
#pragma unroll
        for (int nt = 0; nt < 2; nt++) {
            int cl = 32 * w + 16 * nt;          // block-local c window
            int half = cl >> 6, cc = cl & 63;
#pragma unroll
            for (int mt = 0; mt < 2; mt++) {
                f32x4 acc = {};
#pragma unroll
                for (int ks = 0; ks < 2; ks++) {
                    bf16x8 bfr = ldfrag(Ks, cl, 32 * ks);
                    acc = __builtin_amdgcn_mfma_f32_16x16x32_bf16(qf[mt][ks], bfr, acc, 0, 0, 0);
                }
#pragma unroll
                for (int r = 0; r < 4; r++) {
                    int t = 16 * mt + quad * 4 + r;
                    float p = __expf(acc[r]);
                    rs[mt][r] += p;
                    Pt[half][swz(t, cc + l16)] = f2bf(p);
                }
            }
        }
        __syncthreads();        // Pt writes visible
#pragma unroll
        for (int half = 0; half < 2; half++) {
#pragma unroll
            for (int ks = 0; ks < 2; ks++) {
                bf16x8 vfr = ldfrag(Vs[half], 16 * w, 32 * ks);   // wave w owns d 16w..16w+15
#pragma unroll
                for (int mt = 0; mt < 2; mt++) {
                    bf16x8 af = ldfrag((unsigned short*)Pt[half], 16 * mt, 32 * ks);
                    oacc[mt] = __builtin_amdgcn_mfma_f32_16x16x32_bf16(af, vfr, oacc[mt], 0, 0, 0);
                }
            }
        }
    }
    __syncthreads();

    // ---- rowsum reduce: l16 shfl (each wave covered disjoint c) + cross-wave LDS ----
#pragma unroll
    for (int mt = 0; mt < 2; mt++)
#pragma unroll
        for (int r = 0; r < 4; r++) {
            float s = rs[mt][r];
#pragma unroll
            for (int m = 1; m <= 8; m <<= 1) s += __shfl_xor(s, m, 64);
            if (l16 == 0) red[w][16 * mt + quad * 4 + r] = s;
        }
    __syncthreads();
    if (tid < 32) invs[tid] = 1.0f / (red[0][tid] + red[1][tid] + red[2][tid] + red[3][tid]);
    __syncthreads();

    // ---- O epilogue: scale by invs, store bf16 head-major ----
    {
        int b = bh >> 3, h = bh & 7;
        int d = 16 * w + l16;
#pragma unroll
        for (int mt = 0; mt < 2; mt++)
#pragma unroll
            for (int r = 0; r < 4; r++) {
                int t = 16 * mt + quad * 4 + r;
                oh[(size_t)(b * NT_ + t0 + t) * 512 + h * 64 + d] = f2bf(oacc[mt][r] * invs[t]);
            }
    }

    // ---- phase 3: recompute S^T = mfma(K,Q) from staged K, dwordx4 att stream ----
    float* attbase = attout + ((size_t)bh * NT_ + t0) * 2048;
    float myinv[2];
    myinv[0] = invs[l16];
    myinv[1] = invs[16 + l16];

    for (int c0 = 0; c0 < NC_; c0 += 128) {
        __syncthreads();
        stage_bf<4>(Ks, kbase + (size_t)c0 * 64, 64);
        __syncthreads();
#pragma unroll
        for (int nt = 0; nt < 2; nt++) {
            int cl = 32 * w + 16 * nt;
            bf16x8 af0 = ldfrag(Ks, cl, 0);    // A = K rows (c)
            bf16x8 af1 = ldfrag(Ks, cl, 32);
#pragma unroll
            for (int mt = 0; mt < 2; mt++) {
                f32x4 acc = {};
                acc = __builtin_amdgcn_mfma_f32_16x16x32_bf16(af0, qf[mt][0], acc, 0, 0, 0);
                acc = __builtin_amdgcn_mfma_f32_16x16x32_bf16(af1, qf[mt][1], acc, 0, 0, 0);
                // D[c' = quad*4+r][t' = l16]: lane holds 4 CONSECUTIVE c for one t
                f32x4 o;
#pragma unroll
                for (int r = 0; r < 4; r++) o[r] = __expf(acc[r]) * myinv[mt];
                __builtin_nontemporal_store(o,
                    (f32x4*)(attbase + (size_t)(16 * mt + l16) * 2048 + c0 + cl + quad * 4));
            }
        }
    }
}

// ---------------------------------------------------------------------------
extern "C" void kernel_launch(void* const* d_in, const int* in_sizes, int n_in,
                              void* d_out, int out_size, void* d_ws, size_t ws_size,
                              hipStream_t stream)
{
    (void)in_sizes; (void)n_in; (void)out_size; (void)ws_size;
    const float* queries = (const float*)d_in[0];
    const float* keys    = (const float*)d_in[1];
    const float* values  = (const float*)d_in[2];
    const float* W_At    = (const float*)d_in[3];
    const float* b_At    = (const float*)d_in[4];
    const float* W_Ac    = (const float*)d_in[5];
    const float* b_Ac    = (const float*)d_in[6];
    const float* W_Bc    = (const float*)d_in[7];
    const float* b_Bc    = (const float*)d_in[8];
    const float* W_R     = (const float*)d_in[9];
    const float* b_R     = (const float*)d_in[10];

    float* out0   = (float*)d_out;
    float* attout = out0 + (size_t)B_ * NT_ * EMB_;

    // Workspace: 22,020,096 shorts = 44 MB (known-safe footprint)
    unsigned short* ws = (unsigned short*)d_ws;
    unsigned short* wb = ws;                          // 4 x (512x512) bf16 weights
    unsigned short* qh = ws + 1048576;                // (B,H,NT,64) bf16, normalized
    unsigned short* kh = ws + 3145728;                // (B,H,NC,64) bf16, normalized
    unsigned short* vt = ws + 11534336;               // (B,H,64,NC) bf16 d-major
    unsigned short* oh = ws + 19922944;               // (B,NT,H*64) bf16

    dim3 blk(256);

    // one-shot weight fp32->bf16 (W_At, W_Ac, W_Bc, W_R)
    cvtw<<<dim3(512), blk, 0, stream>>>(W_At, W_Ac, W_Bc, W_R, wb);

    // all three projections, one launch, 128x128 tiles (q/k fused row-normalize)
    proj3<<<dim3(288, 4), blk, 0, stream>>>(queries, keys, values, wb,
                                            b_At, b_Ac, b_Bc, qh, kh, vt);

    // fused scores + online softmax + PV, then att recompute-and-stream
    attn_fused<<<dim3(NT_ / 32, B_ * H_), blk, 0, stream>>>(qh, kh, vt, attout, oh);

    // out = O @ W_R^T + b_R
    outproj<<<dim3(64, 8), blk, 0, stream>>>(oh, wb + 786432, b_R, out0);
}